// Round 1
// baseline (1169.174 us; speedup 1.0000x reference)
//
#include <hip/hip_runtime.h>
#include <hip/hip_bf16.h>

// ---------- fast transcendentals (fp32, ~1e-7 rel err) ----------
__device__ __forceinline__ float fast_rcp(float x) {
    return __builtin_amdgcn_rcpf(x);
}
__device__ __forceinline__ float sigmoidf_(float x) {
    return fast_rcp(1.f + __expf(-x));
}
__device__ __forceinline__ float tanhf_fast(float x) {
    float ax = fabsf(x);
    float e  = __expf(-2.f * ax);
    float t  = (1.f - e) * fast_rcp(1.f + e);
    return copysignf(t, x);
}

// ---------- conv1 (1->10, 5x5 VALID) + maxpool2 + tanh ----------
// x: [B,784] as 28x28, out: [B,10,144] as 10x12x12
__global__ __launch_bounds__(256) void conv1_pool_tanh(
    const float* __restrict__ x, const float* __restrict__ w,
    const float* __restrict__ bias, float* __restrict__ out)
{
    __shared__ float sw[250];
    __shared__ float sb[10];
    int t = threadIdx.x;
    if (t < 250) sw[t] = w[t];
    if (t < 10)  sb[t] = bias[t];
    __syncthreads();

    int gp  = blockIdx.x * 256 + t;          // [0, 4096*144)
    int b   = gp / 144;
    int pix = gp % 144;
    int py = pix / 12, px = pix % 12;

    const float* img = x + (long)b * 784 + (2 * py) * 28 + 2 * px;
    float r[6][6];
#pragma unroll
    for (int ry = 0; ry < 6; ++ry)
#pragma unroll
        for (int rx = 0; rx < 6; ++rx)
            r[ry][rx] = img[ry * 28 + rx];

    float* ob = out + (long)b * 1440 + pix;
    for (int oc = 0; oc < 10; ++oc) {
        float a0 = 0.f, a1 = 0.f, a2 = 0.f, a3 = 0.f;
#pragma unroll
        for (int ky = 0; ky < 5; ++ky)
#pragma unroll
            for (int kx = 0; kx < 5; ++kx) {
                float wv = sw[oc * 25 + ky * 5 + kx];
                a0 += wv * r[ky][kx];
                a1 += wv * r[ky][kx + 1];
                a2 += wv * r[ky + 1][kx];
                a3 += wv * r[ky + 1][kx + 1];
            }
        float m = fmaxf(fmaxf(a0, a1), fmaxf(a2, a3)) + sb[oc];
        ob[oc * 144] = tanhf_fast(m);
    }
}

// ---------- 2D-LSTM (MDLSTM) ----------
// x:[B,CIN,H*W]  Wx:[5H,CIN] Whl,Whu:[5H,HID] bias:[5H]  out:[B,HID,H*W]
// thread = (batch_in_block bl, hidden unit j). Sequential scan over cells.
template<int H, int W, int HID, int CIN, int NB, int CINP>
__global__ __launch_bounds__(NB * HID) void mdlstm_kernel(
    const float* __restrict__ x,  const float* __restrict__ Wx,
    const float* __restrict__ Whl, const float* __restrict__ Whu,
    const float* __restrict__ bias, float* __restrict__ out)
{
    constexpr int G = 5 * HID;
    constexpr int N = H * W;
    __shared__ float sWx[CIN][G];    // transposed: sWx[c][g] = Wx[g][c]
    __shared__ float sWl[HID][G];    // sWl[k][g] = Whl[g][k]
    __shared__ float sWu[HID][G];
    __shared__ float sH[W][NB][HID]; // h row-state (row above, updated in place)
    __shared__ float sC[W][NB][HID]; // c row-state (private per (bl,j,jc))
    __shared__ float sHL[NB][HID];   // h_left
    __shared__ float sX[NB][W][CINP];// staged x for the current row

    const int tid = threadIdx.x;
    const int j  = tid % HID;
    const int bl = tid / HID;
    const long b = (long)blockIdx.x * NB + bl;

    for (int idx = tid; idx < G * CIN; idx += NB * HID)
        sWx[idx % CIN][idx / CIN] = Wx[idx];
    for (int idx = tid; idx < G * HID; idx += NB * HID) {
        sWl[idx % HID][idx / HID] = Whl[idx];
        sWu[idx % HID][idx / HID] = Whu[idx];
    }
    float bs[5];
#pragma unroll
    for (int p = 0; p < 5; ++p) bs[p] = bias[p * HID + j];

    for (int idx = tid; idx < W * NB * HID; idx += NB * HID) {
        (&sH[0][0][0])[idx] = 0.f;
        (&sC[0][0][0])[idx] = 0.f;
    }
    __syncthreads();

    float* ob = out + b * (long)(HID * N);

    for (int i = 0; i < H; ++i) {
        // stage this row's x: sX[bb][jc][c] = x[b, c, i*W+jc]
        for (int idx = tid; idx < NB * CIN * W; idx += NB * HID) {
            int bb  = idx / (CIN * W);
            int rem = idx % (CIN * W);
            int c   = rem / W;
            int jc  = rem % W;
            sX[bb][jc][c] =
                x[((long)blockIdx.x * NB + bb) * (CIN * N) + c * N + i * W + jc];
        }
        sHL[bl][j] = 0.f;     // h_left = 0 at row start
        float c_left = 0.f;
        __syncthreads();

        for (int jc = 0; jc < W; ++jc) {
            float g0 = bs[0], g1 = bs[1], g2 = bs[2], g3 = bs[3], g4 = bs[4];
#pragma unroll
            for (int c = 0; c < CIN; ++c) {
                float xv = sX[bl][jc][c];
                g0 += xv * sWx[c][0 * HID + j];
                g1 += xv * sWx[c][1 * HID + j];
                g2 += xv * sWx[c][2 * HID + j];
                g3 += xv * sWx[c][3 * HID + j];
                g4 += xv * sWx[c][4 * HID + j];
            }
#pragma unroll
            for (int k = 0; k < HID; ++k) {
                float hl = sHL[bl][k];
                g0 += hl * sWl[k][0 * HID + j];
                g1 += hl * sWl[k][1 * HID + j];
                g2 += hl * sWl[k][2 * HID + j];
                g3 += hl * sWl[k][3 * HID + j];
                g4 += hl * sWl[k][4 * HID + j];
            }
#pragma unroll
            for (int k = 0; k < HID; ++k) {
                float hu = sH[jc][bl][k];
                g0 += hu * sWu[k][0 * HID + j];
                g1 += hu * sWu[k][1 * HID + j];
                g2 += hu * sWu[k][2 * HID + j];
                g3 += hu * sWu[k][3 * HID + j];
                g4 += hu * sWu[k][4 * HID + j];
            }
            float c_up = sC[jc][bl][j];
            float cc = sigmoidf_(g1) * c_left + sigmoidf_(g2) * c_up
                     + sigmoidf_(g0) * tanhf_fast(g4);
            float hh = sigmoidf_(g3) * tanhf_fast(cc);
            __syncthreads();              // everyone done reading sHL / sH[jc]
            sHL[bl][j]     = hh;
            sH[jc][bl][j]  = hh;
            sC[jc][bl][j]  = cc;
            c_left = cc;
            ob[j * N + i * W + jc] = hh;
            __syncthreads();              // writes visible before next cell
        }
    }
}

// ---------- conv2 (20->30, 5x5 VALID) + maxpool2 + tanh ----------
// in: [B,20,144] as 20x12x12, out: [B,30,16] as 30x4x4. One block per image.
__global__ __launch_bounds__(256) void conv2_pool_tanh(
    const float* __restrict__ in, const float* __restrict__ w,
    const float* __restrict__ bias, float* __restrict__ out)
{
    __shared__ float sImg[20 * 144];
    __shared__ float sW[30 * 20 * 25];
    __shared__ float sB[30];
    int t = threadIdx.x;
    long b = blockIdx.x;
    for (int idx = t; idx < 2880; idx += 256) sImg[idx] = in[b * 2880 + idx];
    for (int idx = t; idx < 15000; idx += 256) sW[idx] = w[idx];
    if (t < 30) sB[t] = bias[t];
    __syncthreads();

    int pix = t & 15;   // pooled pixel 0..15
    int ocg = t >> 4;   // 0..15, groups of 2 output channels
    if (ocg >= 15) return;   // 240 active threads, no barriers after this
    int py = pix >> 2, px = pix & 3;

    float acc[2][4];
#pragma unroll
    for (int a = 0; a < 2; ++a)
#pragma unroll
        for (int d = 0; d < 4; ++d) acc[a][d] = 0.f;

    for (int ic = 0; ic < 20; ++ic) {
        float r[6][6];
        const float* ip = &sImg[ic * 144 + py * 24 + px * 2];
#pragma unroll
        for (int ry = 0; ry < 6; ++ry)
#pragma unroll
            for (int rx = 0; rx < 6; ++rx)
                r[ry][rx] = ip[ry * 12 + rx];
#pragma unroll
        for (int ko = 0; ko < 2; ++ko) {
            int oc = ocg * 2 + ko;
            const float* wp = &sW[(oc * 20 + ic) * 25];
#pragma unroll
            for (int ky = 0; ky < 5; ++ky)
#pragma unroll
                for (int kx = 0; kx < 5; ++kx) {
                    float wv = wp[ky * 5 + kx];
                    acc[ko][0] += wv * r[ky][kx];
                    acc[ko][1] += wv * r[ky][kx + 1];
                    acc[ko][2] += wv * r[ky + 1][kx];
                    acc[ko][3] += wv * r[ky + 1][kx + 1];
                }
        }
    }
#pragma unroll
    for (int ko = 0; ko < 2; ++ko) {
        int oc = ocg * 2 + ko;
        float m = fmaxf(fmaxf(acc[ko][0], acc[ko][1]),
                        fmaxf(acc[ko][2], acc[ko][3])) + sB[oc];
        out[b * 480 + oc * 16 + pix] = tanhf_fast(m);
    }
}

// ---------- fc1 (640->100) + tanh ----------
// in: [B,640], w: [100,640]. Block = 256 batch rows, one output o per block.
__global__ __launch_bounds__(256) void fc1_tanh(
    const float* __restrict__ in, const float* __restrict__ w,
    const float* __restrict__ bias, float* __restrict__ out)
{
    int t = threadIdx.x;
    int bblk = blockIdx.x & 15;   // 16 batch tiles of 256
    int o    = blockIdx.x >> 4;   // 0..99
    long b = (long)bblk * 256 + t;
    const float* wr = w + o * 640;            // wave-uniform -> scalar loads
    const float* xr = in + b * 640;
    float acc = 0.f;
    for (int k = 0; k < 640; k += 4) {
        float4 wv = *(const float4*)(wr + k);
        float4 xv = *(const float4*)(xr + k);
        acc += wv.x * xv.x + wv.y * xv.y + wv.z * xv.z + wv.w * xv.w;
    }
    out[b * 100 + o] = tanhf_fast(acc + bias[o]);
}

// ---------- fc2 (100->10) + softmax ----------
__global__ __launch_bounds__(64) void fc2_softmax(
    const float* __restrict__ in, const float* __restrict__ w,
    const float* __restrict__ bias, float* __restrict__ out)
{
    long b = (long)blockIdx.x * 64 + threadIdx.x;
    const float* xr = in + b * 100;
    float logit[10];
#pragma unroll
    for (int o = 0; o < 10; ++o) logit[o] = bias[o];
    for (int k = 0; k < 100; ++k) {
        float xv = xr[k];
#pragma unroll
        for (int o = 0; o < 10; ++o) logit[o] += xv * w[o * 100 + k];
    }
    float m = logit[0];
#pragma unroll
    for (int o = 1; o < 10; ++o) m = fmaxf(m, logit[o]);
    float s = 0.f;
#pragma unroll
    for (int o = 0; o < 10; ++o) { logit[o] = __expf(logit[o] - m); s += logit[o]; }
    float inv = fast_rcp(s);
#pragma unroll
    for (int o = 0; o < 10; ++o) out[b * 10 + o] = logit[o] * inv;
}

extern "C" void kernel_launch(void* const* d_in, const int* in_sizes, int n_in,
                              void* d_out, int out_size, void* d_ws, size_t ws_size,
                              hipStream_t stream)
{
    const float* x    = (const float*)d_in[0];
    const float* c1w  = (const float*)d_in[1];
    const float* c1b  = (const float*)d_in[2];
    const float* m1Wx = (const float*)d_in[3];
    const float* m1Wl = (const float*)d_in[4];
    const float* m1Wu = (const float*)d_in[5];
    const float* m1b  = (const float*)d_in[6];
    const float* c2w  = (const float*)d_in[7];
    const float* c2b  = (const float*)d_in[8];
    const float* m2Wx = (const float*)d_in[9];
    const float* m2Wl = (const float*)d_in[10];
    const float* m2Wu = (const float*)d_in[11];
    const float* m2b  = (const float*)d_in[12];
    const float* f1w  = (const float*)d_in[13];
    const float* f1b  = (const float*)d_in[14];
    const float* f2w  = (const float*)d_in[15];
    const float* f2b  = (const float*)d_in[16];
    float* outp = (float*)d_out;

    char* ws = (char*)d_ws;
    float* a1 = (float*)ws;                         // [B,10,144]  23.6 MB
    float* h1 = (float*)(ws + 23592960);            // [B,20,144]  47.2 MB
    float* a2 = a1;                                 // [B,30,16]   reuse (a1 dead)
    float* h2 = h1;                                 // [B,640]     reuse (h1 dead)
    float* f1 = a1;                                 // [B,100]     reuse (a2 dead)

    conv1_pool_tanh<<<2304, 256, 0, stream>>>(x, c1w, c1b, a1);
    mdlstm_kernel<12, 12, 20, 10, 16, 13><<<256, 320, 0, stream>>>(
        a1, m1Wx, m1Wl, m1Wu, m1b, h1);
    conv2_pool_tanh<<<4096, 256, 0, stream>>>(h1, c2w, c2b, a2);
    mdlstm_kernel<4, 4, 40, 30, 8, 31><<<512, 320, 0, stream>>>(
        a2, m2Wx, m2Wl, m2Wu, m2b, h2);
    fc1_tanh<<<1600, 256, 0, stream>>>(h2, f1w, f1b, f1);
    fc2_softmax<<<64, 64, 0, stream>>>(f1, f2w, f2b, outp);
}

// Round 2
// 945.122 us; speedup vs baseline: 1.2371x; 1.2371x over previous
//
#include <hip/hip_runtime.h>
#include <hip/hip_bf16.h>

// ---------- fast transcendentals (fp32, ~1e-7 rel err) ----------
__device__ __forceinline__ float fast_rcp(float x) {
    return __builtin_amdgcn_rcpf(x);
}
__device__ __forceinline__ float sigmoidf_(float x) {
    return fast_rcp(1.f + __expf(-x));
}
__device__ __forceinline__ float tanhf_fast(float x) {
    float ax = fabsf(x);
    float e  = __expf(-2.f * ax);
    float t  = (1.f - e) * fast_rcp(1.f + e);
    return copysignf(t, x);
}

// octet (8-lane) butterfly sum: lanes u and u^{1,2,4} within aligned groups of 8
__device__ __forceinline__ float octet_sum(float v) {
    // xor 1: quad_perm [1,0,3,2] = 0xB1
    v += __int_as_float(__builtin_amdgcn_update_dpp(
            0, __float_as_int(v), 0xB1, 0xF, 0xF, true));
    // xor 2: quad_perm [2,3,0,1] = 0x4E
    v += __int_as_float(__builtin_amdgcn_update_dpp(
            0, __float_as_int(v), 0x4E, 0xF, 0xF, true));
    // xor 4: ds_swizzle BitMode xor_mask=4, and_mask=0x1F
    v += __int_as_float(__builtin_amdgcn_ds_swizzle(__float_as_int(v), 0x101F));
    return v;
}

// ---------- conv1 (1->10, 5x5 VALID) + maxpool2 + tanh ----------
// x: [B,784] as 28x28, out COMPACT: [B,144,10]
__global__ __launch_bounds__(256) void conv1_pool_tanh(
    const float* __restrict__ x, const float* __restrict__ w,
    const float* __restrict__ bias, float* __restrict__ out)
{
    __shared__ float sw[250];
    __shared__ float sb[10];
    int t = threadIdx.x;
    if (t < 250) sw[t] = w[t];
    if (t < 10)  sb[t] = bias[t];
    __syncthreads();

    int gp  = blockIdx.x * 256 + t;          // [0, 4096*144)
    int b   = gp / 144;
    int pix = gp % 144;
    int py = pix / 12, px = pix % 12;

    const float* img = x + (long)b * 784 + (2 * py) * 28 + 2 * px;
    float r[6][6];
#pragma unroll
    for (int ry = 0; ry < 6; ++ry)
#pragma unroll
        for (int rx = 0; rx < 6; ++rx)
            r[ry][rx] = img[ry * 28 + rx];

    float* ob = out + ((long)b * 144 + pix) * 10;
    for (int oc = 0; oc < 10; ++oc) {
        float a0 = 0.f, a1 = 0.f, a2 = 0.f, a3 = 0.f;
#pragma unroll
        for (int ky = 0; ky < 5; ++ky)
#pragma unroll
            for (int kx = 0; kx < 5; ++kx) {
                float wv = sw[oc * 25 + ky * 5 + kx];
                a0 += wv * r[ky][kx];
                a1 += wv * r[ky][kx + 1];
                a2 += wv * r[ky + 1][kx];
                a3 += wv * r[ky + 1][kx + 1];
            }
        float m = fmaxf(fmaxf(a0, a1), fmaxf(a2, a3)) + sb[oc];
        ob[oc] = tanhf_fast(m);
    }
}

// ---------- 2D-LSTM, register-distributed weights ----------
// x: [B, H*W, CIN] compact.  Wx:[5H,CIN] Whl,Whu:[5H,HID] bias:[5H]
// out: [B, HID, H*W]
// thread = (bl, j, u): octet u=0..7 splits padded V=[x(XS)|hl(HS)|hu(HS)]
// into chunks of CH; weights for the chunk live in registers (zero-padded).
template<int H, int W, int HID, int CIN, int NB, int CH, int XS, int HS>
__global__ __launch_bounds__(NB * HID * 8, (CH == 8) ? 4 : 3) void mdlstm_reg(
    const float* __restrict__ x,  const float* __restrict__ Wx,
    const float* __restrict__ Whl, const float* __restrict__ Whu,
    const float* __restrict__ bias, float* __restrict__ out)
{
    constexpr int N   = H * W;
    constexpr int NT  = NB * HID * 8;
    constexpr int XCH = XS / CH;       // chunks in x region
    constexpr int HCH = HS / CH;       // chunks in hl (and hu) region
    static_assert(XCH + 2 * HCH == 8, "octet covers V exactly");

    __shared__ float sX[NB][W][XS];        // current row's x, zero-padded
    __shared__ float sHL[2][NB][HS];       // h_left double buffer
    __shared__ float sHrow[W][NB][HS];     // h of row above (delayed update)

    const int tid = threadIdx.x;
    const int u   = tid & 7;
    const int j   = (tid >> 3) % HID;
    const int bl  = tid / (HID * 8);
    const long b  = (long)blockIdx.x * NB + bl;

    // ---- weights into registers (zero-padded chunks) ----
    float w[5][CH];
#pragma unroll
    for (int p = 0; p < 5; ++p) {
        const int g = p * HID + j;
#pragma unroll
        for (int s = 0; s < CH; ++s) {
            int vidx = u * CH + s;
            float wv = 0.f;
            if (vidx < XS)          { if (vidx < CIN) wv = Wx[g * CIN + vidx]; }
            else if (vidx < XS + HS){ int k = vidx - XS;      if (k < HID) wv = Whl[g * HID + k]; }
            else                    { int k = vidx - XS - HS; if (k < HID) wv = Whu[g * HID + k]; }
            w[p][s] = wv;
        }
    }
    float bs[5];
#pragma unroll
    for (int p = 0; p < 5; ++p) bs[p] = bias[p * HID + j];

    // ---- zero LDS (pads must be 0 and stay 0) ----
    for (int idx = tid; idx < NB * W * XS; idx += NT) (&sX[0][0][0])[idx] = 0.f;
    for (int idx = tid; idx < 2 * NB * HS; idx += NT) (&sHL[0][0][0])[idx] = 0.f;
    for (int idx = tid; idx < W * NB * HS; idx += NT) (&sHrow[0][0][0])[idx] = 0.f;

    // ---- per-thread value pointer: addr = vbase + jc*step_jc + buf*step_buf ----
    const float* vbase; int step_jc, step_buf;
    if (u < XCH) {
        vbase = &sX[bl][0][u * CH];               step_jc = XS;      step_buf = 0;
    } else if (u < XCH + HCH) {
        vbase = &sHL[0][bl][(u - XCH) * CH];      step_jc = 0;       step_buf = NB * HS;
    } else {
        vbase = &sHrow[0][bl][(u - XCH - HCH) * CH]; step_jc = NB * HS; step_buf = 0;
    }

    float c_row[W];
#pragma unroll
    for (int q = 0; q < W; ++q) c_row[q] = 0.f;
    float pend = 0.f;
    float* outb = out + b * (long)(HID * N);

    __syncthreads();

    for (int i = 0; i < H; ++i) {
        // ---- row start: flush delayed h, zero hl buf0, stage x row ----
        if (u == 0) {
            if (i > 0) sHrow[W - 1][bl][j] = pend;
            sHL[0][bl][j] = 0.f;
        }
        for (int idx = tid; idx < NB * W * CIN; idx += NT) {
            int bb = idx / (W * CIN);
            int rr = idx % (W * CIN);
            int jc = rr / CIN, c = rr % CIN;
            sX[bb][jc][c] =
                x[(((long)blockIdx.x * NB + bb) * N + i * W + jc) * CIN + c];
        }
        float c_left = 0.f;
        __syncthreads();

#pragma unroll
        for (int jc = 0; jc < W; ++jc) {
            const float* vp = vbase + jc * step_jc + ((jc & 1) ? step_buf : 0);
            float vv[CH];
#pragma unroll
            for (int q = 0; q < CH / 4; ++q) {
                float4 t4 = *(const float4*)(vp + 4 * q);
                vv[4 * q + 0] = t4.x; vv[4 * q + 1] = t4.y;
                vv[4 * q + 2] = t4.z; vv[4 * q + 3] = t4.w;
            }
            float g0 = 0.f, g1 = 0.f, g2 = 0.f, g3 = 0.f, g4 = 0.f;
#pragma unroll
            for (int s = 0; s < CH; ++s) {
                g0 = fmaf(w[0][s], vv[s], g0);
                g1 = fmaf(w[1][s], vv[s], g1);
                g2 = fmaf(w[2][s], vv[s], g2);
                g3 = fmaf(w[3][s], vv[s], g3);
                g4 = fmaf(w[4][s], vv[s], g4);
            }
            g0 = octet_sum(g0) + bs[0];
            g1 = octet_sum(g1) + bs[1];
            g2 = octet_sum(g2) + bs[2];
            g3 = octet_sum(g3) + bs[3];
            g4 = octet_sum(g4) + bs[4];

            float ig  = sigmoidf_(g0), f1g = sigmoidf_(g1), f2g = sigmoidf_(g2);
            float og  = sigmoidf_(g3), gg  = tanhf_fast(g4);
            float cc  = f1g * c_left + f2g * c_row[jc] + ig * gg;
            float hh  = og * tanhf_fast(cc);
            c_row[jc] = cc;
            c_left    = cc;
            if (u == 0) {
                sHL[(jc + 1) & 1][bl][j] = hh;
                if (jc > 0) sHrow[jc - 1][bl][j] = pend;
                outb[j * N + i * W + jc] = hh;
            }
            pend = hh;
            __syncthreads();
        }
    }
}

// ---------- conv2 (20->30, 5x5 VALID) + maxpool2 + tanh ----------
// in: [B,20,144] as 20x12x12, out COMPACT: [B,16,30]. One block per image.
__global__ __launch_bounds__(256) void conv2_pool_tanh(
    const float* __restrict__ in, const float* __restrict__ w,
    const float* __restrict__ bias, float* __restrict__ out)
{
    __shared__ float sImg[20 * 144];
    __shared__ float sW[30 * 20 * 25];
    __shared__ float sB[30];
    int t = threadIdx.x;
    long b = blockIdx.x;
    for (int idx = t; idx < 2880; idx += 256) sImg[idx] = in[b * 2880 + idx];
    for (int idx = t; idx < 15000; idx += 256) sW[idx] = w[idx];
    if (t < 30) sB[t] = bias[t];
    __syncthreads();

    int pix = t & 15;   // pooled pixel 0..15
    int ocg = t >> 4;   // 0..15, groups of 2 output channels
    if (ocg >= 15) return;   // 240 active threads, no barriers after this
    int py = pix >> 2, px = pix & 3;

    float acc[2][4];
#pragma unroll
    for (int a = 0; a < 2; ++a)
#pragma unroll
        for (int d = 0; d < 4; ++d) acc[a][d] = 0.f;

    for (int ic = 0; ic < 20; ++ic) {
        float r[6][6];
        const float* ip = &sImg[ic * 144 + py * 24 + px * 2];
#pragma unroll
        for (int ry = 0; ry < 6; ++ry)
#pragma unroll
            for (int rx = 0; rx < 6; ++rx)
                r[ry][rx] = ip[ry * 12 + rx];
#pragma unroll
        for (int ko = 0; ko < 2; ++ko) {
            int oc = ocg * 2 + ko;
            const float* wp = &sW[(oc * 20 + ic) * 25];
#pragma unroll
            for (int ky = 0; ky < 5; ++ky)
#pragma unroll
                for (int kx = 0; kx < 5; ++kx) {
                    float wv = wp[ky * 5 + kx];
                    acc[ko][0] += wv * r[ky][kx];
                    acc[ko][1] += wv * r[ky][kx + 1];
                    acc[ko][2] += wv * r[ky + 1][kx];
                    acc[ko][3] += wv * r[ky + 1][kx + 1];
                }
        }
    }
#pragma unroll
    for (int ko = 0; ko < 2; ++ko) {
        int oc = ocg * 2 + ko;
        float m = fmaxf(fmaxf(acc[ko][0], acc[ko][1]),
                        fmaxf(acc[ko][2], acc[ko][3])) + sB[oc];
        out[b * 480 + pix * 30 + oc] = tanhf_fast(m);
    }
}

// ---------- fc1 (640->100) + tanh ----------
__global__ __launch_bounds__(256) void fc1_tanh(
    const float* __restrict__ in, const float* __restrict__ w,
    const float* __restrict__ bias, float* __restrict__ out)
{
    int t = threadIdx.x;
    int bblk = blockIdx.x & 15;   // 16 batch tiles of 256
    int o    = blockIdx.x >> 4;   // 0..99
    long b = (long)bblk * 256 + t;
    const float* wr = w + o * 640;            // wave-uniform -> scalar loads
    const float* xr = in + b * 640;
    float acc = 0.f;
    for (int k = 0; k < 640; k += 4) {
        float4 wv = *(const float4*)(wr + k);
        float4 xv = *(const float4*)(xr + k);
        acc += wv.x * xv.x + wv.y * xv.y + wv.z * xv.z + wv.w * xv.w;
    }
    out[b * 100 + o] = tanhf_fast(acc + bias[o]);
}

// ---------- fc2 (100->10) + softmax ----------
__global__ __launch_bounds__(64) void fc2_softmax(
    const float* __restrict__ in, const float* __restrict__ w,
    const float* __restrict__ bias, float* __restrict__ out)
{
    long b = (long)blockIdx.x * 64 + threadIdx.x;
    const float* xr = in + b * 100;
    float logit[10];
#pragma unroll
    for (int o = 0; o < 10; ++o) logit[o] = bias[o];
    for (int k = 0; k < 100; ++k) {
        float xv = xr[k];
#pragma unroll
        for (int o = 0; o < 10; ++o) logit[o] += xv * w[o * 100 + k];
    }
    float m = logit[0];
#pragma unroll
    for (int o = 1; o < 10; ++o) m = fmaxf(m, logit[o]);
    float s = 0.f;
#pragma unroll
    for (int o = 0; o < 10; ++o) { logit[o] = __expf(logit[o] - m); s += logit[o]; }
    float inv = fast_rcp(s);
#pragma unroll
    for (int o = 0; o < 10; ++o) out[b * 10 + o] = logit[o] * inv;
}

extern "C" void kernel_launch(void* const* d_in, const int* in_sizes, int n_in,
                              void* d_out, int out_size, void* d_ws, size_t ws_size,
                              hipStream_t stream)
{
    const float* x    = (const float*)d_in[0];
    const float* c1w  = (const float*)d_in[1];
    const float* c1b  = (const float*)d_in[2];
    const float* m1Wx = (const float*)d_in[3];
    const float* m1Wl = (const float*)d_in[4];
    const float* m1Wu = (const float*)d_in[5];
    const float* m1b  = (const float*)d_in[6];
    const float* c2w  = (const float*)d_in[7];
    const float* c2b  = (const float*)d_in[8];
    const float* m2Wx = (const float*)d_in[9];
    const float* m2Wl = (const float*)d_in[10];
    const float* m2Wu = (const float*)d_in[11];
    const float* m2b  = (const float*)d_in[12];
    const float* f1w  = (const float*)d_in[13];
    const float* f1b  = (const float*)d_in[14];
    const float* f2w  = (const float*)d_in[15];
    const float* f2b  = (const float*)d_in[16];
    float* outp = (float*)d_out;

    char* ws = (char*)d_ws;
    float* a1 = (float*)ws;                         // [B,144,10]  23.6 MB
    float* h1 = (float*)(ws + 23592960);            // [B,20,144]  47.2 MB
    float* a2 = a1;                                 // [B,16,30]   reuse (a1 dead)
    float* h2 = h1;                                 // [B,640]     reuse (h1 dead)
    float* f1 = a1;                                 // [B,100]     reuse (a2 dead)

    conv1_pool_tanh<<<2304, 256, 0, stream>>>(x, c1w, c1b, a1);
    // V = [x:16 | hl:24 | hu:24] = 64 = 8 chunks x 8
    mdlstm_reg<12, 12, 20, 10, 2, 8, 16, 24><<<2048, 320, 0, stream>>>(
        a1, m1Wx, m1Wl, m1Wu, m1b, h1);
    conv2_pool_tanh<<<4096, 256, 0, stream>>>(h1, c2w, c2b, a2);
    // V = [x:32 | hl:48 | hu:48] = 128 = 8 chunks x 16
    mdlstm_reg<4, 4, 40, 30, 1, 16, 32, 48><<<4096, 320, 0, stream>>>(
        a2, m2Wx, m2Wl, m2Wu, m2b, h2);
    fc1_tanh<<<1600, 256, 0, stream>>>(h2, f1w, f1b, f1);
    fc2_softmax<<<64, 64, 0, stream>>>(f1, f2w, f2b, outp);
}

// Round 3
// 464.524 us; speedup vs baseline: 2.5169x; 2.0346x over previous
//
#include <hip/hip_runtime.h>
#include <hip/hip_bf16.h>

typedef __attribute__((ext_vector_type(8))) short sh8;
typedef __attribute__((ext_vector_type(4))) float f4;
typedef unsigned short ushort_t;
typedef unsigned int uint_t;

// ---------- fast transcendentals (fp32) ----------
__device__ __forceinline__ float fast_rcp(float x) {
    return __builtin_amdgcn_rcpf(x);
}
__device__ __forceinline__ float sigmoidf_(float x) {
    return fast_rcp(1.f + __expf(-x));
}
__device__ __forceinline__ float tanhf_fast(float x) {
    float ax = fabsf(x);
    float e  = __expf(-2.f * ax);
    float t  = (1.f - e) * fast_rcp(1.f + e);
    return copysignf(t, x);
}

// ---------- bf16 split helpers (truncation; hi+lo ~ 2^-17 rel) ----------
__device__ __forceinline__ ushort_t bf16hi(float x) {
    return (ushort_t)(__float_as_uint(x) >> 16);
}
__device__ __forceinline__ float bf16tof(ushort_t u) {
    return __uint_as_float(((uint_t)u) << 16);
}

// ---------- conv1 (1->10, 5x5 VALID) + maxpool2 + tanh ----------
// x: [B,784] as 28x28, out COMPACT: [B,144,10]
__global__ __launch_bounds__(256) void conv1_pool_tanh(
    const float* __restrict__ x, const float* __restrict__ w,
    const float* __restrict__ bias, float* __restrict__ out)
{
    __shared__ float sw[250];
    __shared__ float sb[10];
    int t = threadIdx.x;
    if (t < 250) sw[t] = w[t];
    if (t < 10)  sb[t] = bias[t];
    __syncthreads();

    int gp  = blockIdx.x * 256 + t;
    int b   = gp / 144;
    int pix = gp % 144;
    int py = pix / 12, px = pix % 12;

    const float* img = x + (long)b * 784 + (2 * py) * 28 + 2 * px;
    float r[6][6];
#pragma unroll
    for (int ry = 0; ry < 6; ++ry)
#pragma unroll
        for (int rx = 0; rx < 6; ++rx)
            r[ry][rx] = img[ry * 28 + rx];

    float* ob = out + ((long)b * 144 + pix) * 10;
    for (int oc = 0; oc < 10; ++oc) {
        float a0 = 0.f, a1 = 0.f, a2 = 0.f, a3 = 0.f;
#pragma unroll
        for (int ky = 0; ky < 5; ++ky)
#pragma unroll
            for (int kx = 0; kx < 5; ++kx) {
                float wv = sw[oc * 25 + ky * 5 + kx];
                a0 += wv * r[ky][kx];
                a1 += wv * r[ky][kx + 1];
                a2 += wv * r[ky + 1][kx];
                a3 += wv * r[ky + 1][kx + 1];
            }
        float m = fmaxf(fmaxf(a0, a1), fmaxf(a2, a3)) + sb[oc];
        ob[oc] = tanhf_fast(m);
    }
}

// ---------- MFMA 2D-LSTM ----------
// x compact [B, H*W, CIN]; Wx [5H,CIN], Whl/Whu [5H,HID], bias [5H]
// out compact [B, H*W, HID].
// Block = 16 batch. NW waves; wave w owns M-tile w (rows 16w..16w+15 of 5H pad).
// V (K dim) = [x:0..CIN | hl | hu | pad] to KV; stored bf16 hi (0..KV) + lo (KV..2KV).
// Gates via 3-term bf16x2 split MFMA; fp32 epilogue 1 value/thread.
template<int H, int W, int HID, int CIN, int KV, int NK, int NW, int VSTR, int GSTR>
__global__ __launch_bounds__(NW * 64) void mdlstm_mfma(
    const float* __restrict__ x, const float* __restrict__ Wx,
    const float* __restrict__ Whl, const float* __restrict__ Whu,
    const float* __restrict__ bias, float* __restrict__ out)
{
    constexpr int N    = H * W;
    constexpr int NT   = NW * 64;
    constexpr int NEPI = 16 * HID;          // epilogue threads
    constexpr int HL0  = CIN, HU0 = CIN + HID;
    constexpr int NXA  = 16 * CIN;          // x-assembly threads
    constexpr int NSTG = 16 * W * CIN;      // elements per staged row
    static_assert(NW * 16 >= 5 * HID, "tiles cover gate rows");
    static_assert(KV >= CIN + 2 * HID, "K covers V");
    static_assert(NEPI <= NT && NXA <= NT, "thread budget");

    __shared__ ushort_t sV[16][VSTR];       // [batch][k]: hi 0..KV, lo KV..2KV
    __shared__ float    sG[16][GSTR];       // gates transposed [batch][row]
    __shared__ uint_t   sHrow[W][16][HID];  // packed (hi<<16)|lo of row-above h
    __shared__ uint_t   sXrow[2][W][16][CIN]; // packed x, double-buffered rows

    const int tid  = threadIdx.x;
    const int lane = tid & 63;
    const int wid  = tid >> 6;
    const int lr   = lane & 15;             // A row-in-tile / B col / C col
    const int lg   = lane >> 4;             // k-group / C row-group
    const long bB  = (long)blockIdx.x * 16;

    // ---- persistent A-frags (weights hi/lo) + bias C-in frag ----
    sh8 Ah[NK], Al[NK];
    {
        const int r = wid * 16 + lr;
#pragma unroll
        for (int ks = 0; ks < NK; ++ks) {
#pragma unroll
            for (int e = 0; e < 8; ++e) {
                int k = ks * 32 + lg * 8 + e;
                float wv = 0.f;
                if (r < 5 * HID) {
                    if (k < CIN)            wv = Wx[r * CIN + k];
                    else if (k < HL0 + HID) wv = Whl[r * HID + (k - HL0)];
                    else if (k < HU0 + HID) wv = Whu[r * HID + (k - HU0)];
                }
                ushort_t hi = bf16hi(wv);
                Ah[ks][e] = (short)hi;
                Al[ks][e] = (short)bf16hi(wv - bf16tof(hi));
            }
        }
    }
    f4 biasF;
#pragma unroll
    for (int q = 0; q < 4; ++q) {
        int rr = wid * 16 + lg * 4 + q;
        biasF[q] = (rr < 5 * HID) ? bias[rr] : 0.f;
    }

    // ---- zero sV (pads must stay 0) and sHrow ----
    for (int idx = tid; idx < 16 * VSTR; idx += NT) (&sV[0][0])[idx] = 0;
    for (int idx = tid; idx < W * 16 * HID; idx += NT) (&sHrow[0][0][0])[idx] = 0;

    // ---- stage row 0 ----
    for (int idx = tid; idx < NSTG; idx += NT) {
        int batch = idx / (W * CIN);
        int rr    = idx % (W * CIN);
        float xv  = x[(bB + batch) * (N * CIN) + rr];
        ushort_t hi = bf16hi(xv);
        ushort_t lo = bf16hi(xv - bf16tof(hi));
        sXrow[0][rr / CIN][batch][rr % CIN] = ((uint_t)hi << 16) | lo;
    }
    __syncthreads();
    if (tid < NXA) {   // assemble x for cell (0,0); hl/hu already zero
        int batch = tid & 15, c = tid >> 4;
        uint_t xv = sXrow[0][0][batch][c];
        sV[batch][c]      = (ushort_t)(xv >> 16);
        sV[batch][KV + c] = (ushort_t)(xv & 0xffff);
    }
    __syncthreads();

    const int batch_e = tid & 15, j_e = tid >> 4;   // epilogue mapping (tid<NEPI)
    float c_row[W];
#pragma unroll
    for (int q = 0; q < W; ++q) c_row[q] = 0.f;

    for (int i = 0; i < H; ++i) {
        float c_left = 0.f;
#pragma unroll
        for (int jc = 0; jc < W; ++jc) {
            // ============ Phase A: MFMA gates ============
            {
                sh8 Bh[NK];
#pragma unroll
                for (int ks = 0; ks < NK; ++ks)
                    Bh[ks] = *(const sh8*)&sV[lr][ks * 32 + lg * 8];
                f4 acc = __builtin_amdgcn_mfma_f32_16x16x32_bf16(
                             Ah[0], Bh[0], biasF, 0, 0, 0);
#pragma unroll
                for (int ks = 1; ks < NK; ++ks)
                    acc = __builtin_amdgcn_mfma_f32_16x16x32_bf16(
                              Ah[ks], Bh[ks], acc, 0, 0, 0);
#pragma unroll
                for (int ks = 0; ks < NK; ++ks) {
                    sh8 Bl = *(const sh8*)&sV[lr][KV + ks * 32 + lg * 8];
                    acc = __builtin_amdgcn_mfma_f32_16x16x32_bf16(
                              Ah[ks], Bl, acc, 0, 0, 0);
                }
#pragma unroll
                for (int ks = 0; ks < NK; ++ks)
                    acc = __builtin_amdgcn_mfma_f32_16x16x32_bf16(
                              Al[ks], Bh[ks], acc, 0, 0, 0);
                *(f4*)&sG[lr][wid * 16 + lg * 4] = acc;
            }
            // stage next row's x during first cell of this row
            if (jc == 0 && i + 1 < H) {
                const int nb = (i + 1) & 1;
                for (int idx = tid; idx < NSTG; idx += NT) {
                    int batch = idx / (W * CIN);
                    int rr    = idx % (W * CIN);
                    float xv  = x[(bB + batch) * (N * CIN) + (i + 1) * (W * CIN) + rr];
                    ushort_t hi = bf16hi(xv);
                    ushort_t lo = bf16hi(xv - bf16tof(hi));
                    sXrow[nb][rr / CIN][batch][rr % CIN] = ((uint_t)hi << 16) | lo;
                }
            }
            __syncthreads();
            // ============ Phase B: epilogue + next-cell V assembly ============
            if (tid < NEPI) {
                float g[5];
#pragma unroll
                for (int p = 0; p < 5; ++p) g[p] = sG[batch_e][j_e + HID * p];
                float ig  = sigmoidf_(g[0]), f1g = sigmoidf_(g[1]);
                float f2g = sigmoidf_(g[2]), og  = sigmoidf_(g[3]);
                float gg  = tanhf_fast(g[4]);
                float cc  = f1g * c_left + f2g * c_row[jc] + ig * gg;
                float hh  = og * tanhf_fast(cc);
                c_row[jc] = cc;
                c_left    = cc;
                ushort_t hhi = bf16hi(hh);
                ushort_t hlo = bf16hi(hh - bf16tof(hhi));
                if (jc < W - 1) {            // h_left for next cell in row
                    sV[batch_e][HL0 + j_e]      = hhi;
                    sV[batch_e][KV + HL0 + j_e] = hlo;
                }
                sHrow[jc][batch_e][j_e] = ((uint_t)hhi << 16) | hlo;
                out[(bB + batch_e) * (long)(N * HID) + (i * W + jc) * HID + j_e] = hh;
            }
            if (i * W + jc < H * W - 1) {    // assemble V for next cell
                const int jc2 = (jc == W - 1) ? 0 : jc + 1;
                const int ib  = (jc == W - 1) ? ((i + 1) & 1) : (i & 1);
                if (tid >= NT - NEPI) {      // hu from sHrow
                    int t2 = tid - (NT - NEPI);
                    int batch = t2 & 15, j2 = t2 >> 4;
                    uint_t hv = sHrow[jc2][batch][j2];
                    sV[batch][HU0 + j2]      = (ushort_t)(hv >> 16);
                    sV[batch][KV + HU0 + j2] = (ushort_t)(hv & 0xffff);
                }
                if (tid < NXA) {             // x from sXrow
                    int batch = tid & 15, c = tid >> 4;
                    uint_t xv = sXrow[ib][jc2][batch][c];
                    sV[batch][c]      = (ushort_t)(xv >> 16);
                    sV[batch][KV + c] = (ushort_t)(xv & 0xffff);
                }
                if (jc == W - 1 && tid < NEPI) {   // zero h_left at row start
                    sV[batch_e][HL0 + j_e]      = 0;
                    sV[batch_e][KV + HL0 + j_e] = 0;
                }
            }
            __syncthreads();
        }
    }
}

// ---------- conv2 (20->30, 5x5 VALID) + maxpool2 + tanh ----------
// in COMPACT [B,144,20], out COMPACT [B,16,30]. One block per image.
__global__ __launch_bounds__(256) void conv2_pool_tanh(
    const float* __restrict__ in, const float* __restrict__ w,
    const float* __restrict__ bias, float* __restrict__ out)
{
    __shared__ float sImg[20 * 144];
    __shared__ float sW[30 * 20 * 25];
    __shared__ float sB[30];
    int t = threadIdx.x;
    long b = blockIdx.x;
    for (int idx = t; idx < 2880; idx += 256) {
        int pix = idx / 20, ic = idx % 20;
        sImg[ic * 144 + pix] = in[b * 2880 + idx];
    }
    for (int idx = t; idx < 15000; idx += 256) sW[idx] = w[idx];
    if (t < 30) sB[t] = bias[t];
    __syncthreads();

    int pix = t & 15;
    int ocg = t >> 4;
    if (ocg >= 15) return;
    int py = pix >> 2, px = pix & 3;

    float acc[2][4];
#pragma unroll
    for (int a = 0; a < 2; ++a)
#pragma unroll
        for (int d = 0; d < 4; ++d) acc[a][d] = 0.f;

    for (int ic = 0; ic < 20; ++ic) {
        float r[6][6];
        const float* ip = &sImg[ic * 144 + py * 24 + px * 2];
#pragma unroll
        for (int ry = 0; ry < 6; ++ry)
#pragma unroll
            for (int rx = 0; rx < 6; ++rx)
                r[ry][rx] = ip[ry * 12 + rx];
#pragma unroll
        for (int ko = 0; ko < 2; ++ko) {
            int oc = ocg * 2 + ko;
            const float* wp = &sW[(oc * 20 + ic) * 25];
#pragma unroll
            for (int ky = 0; ky < 5; ++ky)
#pragma unroll
                for (int kx = 0; kx < 5; ++kx) {
                    float wv = wp[ky * 5 + kx];
                    acc[ko][0] += wv * r[ky][kx];
                    acc[ko][1] += wv * r[ky][kx + 1];
                    acc[ko][2] += wv * r[ky + 1][kx];
                    acc[ko][3] += wv * r[ky + 1][kx + 1];
                }
        }
    }
#pragma unroll
    for (int ko = 0; ko < 2; ++ko) {
        int oc = ocg * 2 + ko;
        float m = fmaxf(fmaxf(acc[ko][0], acc[ko][1]),
                        fmaxf(acc[ko][2], acc[ko][3])) + sB[oc];
        out[b * 480 + pix * 30 + oc] = tanhf_fast(m);
    }
}

// ---------- fc1 (640->100) + tanh ----------
// in COMPACT [B,16,40] (k' = pix*40+hid); w [100,640] with k = hid*16+pix.
__global__ __launch_bounds__(256) void fc1_tanh(
    const float* __restrict__ in, const float* __restrict__ w,
    const float* __restrict__ bias, float* __restrict__ out)
{
    int t = threadIdx.x;
    int bblk = blockIdx.x & 15;
    int o    = blockIdx.x >> 4;
    long b = (long)bblk * 256 + t;
    const float* wr = w + o * 640;       // uniform -> scalar loads
    const float* xr = in + b * 640;
    float acc = 0.f;
#pragma unroll 4
    for (int pix = 0; pix < 16; ++pix) {
        const float* xp = xr + pix * 40;
#pragma unroll
        for (int hid = 0; hid < 40; hid += 4) {
            float4 xv = *(const float4*)(xp + hid);
            acc += wr[(hid + 0) * 16 + pix] * xv.x
                 + wr[(hid + 1) * 16 + pix] * xv.y
                 + wr[(hid + 2) * 16 + pix] * xv.z
                 + wr[(hid + 3) * 16 + pix] * xv.w;
        }
    }
    out[b * 100 + o] = tanhf_fast(acc + bias[o]);
}

// ---------- fc2 (100->10) + softmax ----------
__global__ __launch_bounds__(64) void fc2_softmax(
    const float* __restrict__ in, const float* __restrict__ w,
    const float* __restrict__ bias, float* __restrict__ out)
{
    long b = (long)blockIdx.x * 64 + threadIdx.x;
    const float* xr = in + b * 100;
    float logit[10];
#pragma unroll
    for (int o = 0; o < 10; ++o) logit[o] = bias[o];
    for (int k = 0; k < 100; ++k) {
        float xv = xr[k];
#pragma unroll
        for (int o = 0; o < 10; ++o) logit[o] += xv * w[o * 100 + k];
    }
    float m = logit[0];
#pragma unroll
    for (int o = 1; o < 10; ++o) m = fmaxf(m, logit[o]);
    float s = 0.f;
#pragma unroll
    for (int o = 0; o < 10; ++o) { logit[o] = __expf(logit[o] - m); s += logit[o]; }
    float inv = fast_rcp(s);
#pragma unroll
    for (int o = 0; o < 10; ++o) out[b * 10 + o] = logit[o] * inv;
}

extern "C" void kernel_launch(void* const* d_in, const int* in_sizes, int n_in,
                              void* d_out, int out_size, void* d_ws, size_t ws_size,
                              hipStream_t stream)
{
    const float* x    = (const float*)d_in[0];
    const float* c1w  = (const float*)d_in[1];
    const float* c1b  = (const float*)d_in[2];
    const float* m1Wx = (const float*)d_in[3];
    const float* m1Wl = (const float*)d_in[4];
    const float* m1Wu = (const float*)d_in[5];
    const float* m1b  = (const float*)d_in[6];
    const float* c2w  = (const float*)d_in[7];
    const float* c2b  = (const float*)d_in[8];
    const float* m2Wx = (const float*)d_in[9];
    const float* m2Wl = (const float*)d_in[10];
    const float* m2Wu = (const float*)d_in[11];
    const float* m2b  = (const float*)d_in[12];
    const float* f1w  = (const float*)d_in[13];
    const float* f1b  = (const float*)d_in[14];
    const float* f2w  = (const float*)d_in[15];
    const float* f2b  = (const float*)d_in[16];
    float* outp = (float*)d_out;

    char* ws = (char*)d_ws;
    float* a1 = (float*)ws;                 // [B,144,10] 23.6 MB
    float* h1 = (float*)(ws + 23592960);    // [B,144,20] 47.2 MB
    float* a2 = a1;                         // [B,16,30] reuse
    float* h2 = h1;                         // [B,16,40] reuse
    float* f1 = a1;                         // [B,100]   reuse

    conv1_pool_tanh<<<2304, 256, 0, stream>>>(x, c1w, c1b, a1);
    // m1: V=[x10|hl20|hu20] pad KV=64, NK=2, 7 M-tiles (112 rows)
    mdlstm_mfma<12, 12, 20, 10, 64, 2, 7, 136, 116><<<256, 448, 0, stream>>>(
        a1, m1Wx, m1Wl, m1Wu, m1b, h1);
    conv2_pool_tanh<<<4096, 256, 0, stream>>>(h1, c2w, c2b, a2);
    // m2: V=[x30|hl40|hu40] pad KV=128, NK=4, 13 M-tiles (208 rows)
    mdlstm_mfma<4, 4, 40, 30, 128, 4, 13, 264, 212><<<256, 832, 0, stream>>>(
        a2, m2Wx, m2Wl, m2Wu, m2b, h2);
    fc1_tanh<<<1600, 256, 0, stream>>>(h2, f1w, f1b, f1);
    fc2_softmax<<<64, 64, 0, stream>>>(f1, f2w, f2b, outp);
}